// Round 1
// baseline (1723.763 us; speedup 1.0000x reference)
//
#include <hip/hip_runtime.h>
#include <hip/hip_bf16.h>

// Ring-unroll gather: out[p, dif, j] = x[p, R(dif,j), C(dif,j)]
// x: (B*C=512 planes, H=512, W=512) fp32 ; out: (planes, 256, 2048) fp32
// Closed-form index map (H even): i = 255-dif, el = 2*dif+1, cR = i+el = W-1-i.
// Segments along j (lengths): [i:corner TL][el:top][2i:corner TR][el:right]
//                             [2i:corner BR][el:bottom rev][2i:corner BL][el:left rev][i:corner TL]
// j in [2044,2048) replicates j-2044.

#define RG_H  512
#define RG_W  512
#define RG_NR 256    // output rows per plane
#define RG_OW 2048   // output cols per plane

__device__ __forceinline__ void ring_rc(int j, int i, int el, int& r, int& c)
{
    const int cR = i + el;          // == W-1-i
    if (j >= 2044) j -= 2044;       // tail 4 cols replicate first 4
    const int b0 = i;
    const int b1 = b0 + el;
    const int b2 = b1 + 2 * i;
    const int b3 = b2 + el;
    const int b4 = b3 + 2 * i;
    const int b5 = b4 + el;
    const int b6 = b5 + 2 * i;
    const int b7 = b6 + el;         // == 2044 - i

    if (j < b0)      { r = i;              c = i;              }
    else if (j < b1) { r = i;              c = i + (j - b0);   }
    else if (j < b2) { r = i;              c = cR;             }
    else if (j < b3) { r = i + (j - b2);   c = cR;             }
    else if (j < b4) { r = cR;             c = cR;             }
    else if (j < b5) { r = cR;             c = cR - (j - b4);  }
    else if (j < b6) { r = cR;             c = i;              }
    else if (j < b7) { r = cR - (j - b6);  c = i;              }
    else             { r = i;              c = i;              }
}

__global__ __launch_bounds__(256) void SqRL_gather_kernel(
    const float* __restrict__ x, float* __restrict__ out, int total_quads)
{
    const int tid = blockIdx.x * 256 + threadIdx.x;   // one thread = 4 output elems
    if (tid >= total_quads) return;

    // per-plane quads = 256 rows * 512 quads/row = 2^17 ; quads/row = 2^9
    const int p   = tid >> 17;
    const int t   = tid & 131071;
    const int dif = t >> 9;
    const int jq  = t & 511;
    const int j0  = jq << 2;

    const int i  = 255 - dif;
    const int el = 2 * dif + 1;

    const float* __restrict__ plane = x + (size_t)p * (RG_H * RG_W);

    float4 v;
    int r, c;
    ring_rc(j0 + 0, i, el, r, c); v.x = plane[r * RG_W + c];
    ring_rc(j0 + 1, i, el, r, c); v.y = plane[r * RG_W + c];
    ring_rc(j0 + 2, i, el, r, c); v.z = plane[r * RG_W + c];
    ring_rc(j0 + 3, i, el, r, c); v.w = plane[r * RG_W + c];

    reinterpret_cast<float4*>(out)[tid] = v;
}

extern "C" void kernel_launch(void* const* d_in, const int* in_sizes, int n_in,
                              void* d_out, int out_size, void* d_ws, size_t ws_size,
                              hipStream_t stream)
{
    const float* x = (const float*)d_in[0];
    float* out = (float*)d_out;

    const int planes = in_sizes[0] / (RG_H * RG_W);        // 16*32 = 512
    const int total_quads = planes * RG_NR * (RG_OW / 4);  // 67,108,864
    const int blocks = (total_quads + 255) / 256;          // 262,144

    SqRL_gather_kernel<<<blocks, 256, 0, stream>>>(x, out, total_quads);
}